// Round 6
// baseline (1494.233 us; speedup 1.0000x reference)
//
#include <hip/hip_runtime.h>
#include <stdint.h>

typedef unsigned short u16;
typedef unsigned char u8;
typedef float f32x4 __attribute__((ext_vector_type(4)));
typedef float f32x2 __attribute__((ext_vector_type(2)));
typedef short s16x8 __attribute__((ext_vector_type(8)));
typedef unsigned short u16x4 __attribute__((ext_vector_type(4)));

#define NB 16
#define NT 9
#define NN 1024
#define NDIM 768
#define NH 8
#define NHD 96
#define NM (NB*NT*NN)          // 147456 rows
#define NQK 1536               // q|k columns
#define PLANE (NN*NDIM)        // 786432 elems per (b,t) plane
#define SCALE_F 0.10206207261596575f   // 96^-0.5

typedef __attribute__((address_space(1))) const void gvoid_t;
typedef __attribute__((address_space(3))) void lvoid_t;
#define GLOAD_LDS16(gp, lp) __builtin_amdgcn_global_load_lds((gvoid_t*)(gp), (lvoid_t*)(lp), 16, 0, 0)

// Packed operand layout (K=768): matrix[row][col] at u16 index
//   (row>>4)*12288 + (col>>5)*512 + ((row&15) + 16*((col>>3)&3))*8 + (col&7)
// = [row-group16][k-chunk32] slabs of 1KB; one MFMA fragment per slab.
__device__ __forceinline__ size_t gpack(int row, int col) {
    return (size_t)(row >> 4) * 12288 + ((col >> 5) * 512)
         + (((row & 15) + 16 * ((col >> 3) & 3)) * 8) + (col & 7);
}

__device__ __forceinline__ unsigned f2bf_u(float x) {
    unsigned u = __builtin_bit_cast(unsigned, x);
    return (u + 0x7FFFu + ((u >> 16) & 1u)) >> 16;   // RNE
}
__device__ __forceinline__ void cvt8(uint4 v, float* f) {
    f[0] = __builtin_bit_cast(float, v.x << 16);
    f[1] = __builtin_bit_cast(float, v.x & 0xFFFF0000u);
    f[2] = __builtin_bit_cast(float, v.y << 16);
    f[3] = __builtin_bit_cast(float, v.y & 0xFFFF0000u);
    f[4] = __builtin_bit_cast(float, v.z << 16);
    f[5] = __builtin_bit_cast(float, v.z & 0xFFFF0000u);
    f[6] = __builtin_bit_cast(float, v.w << 16);
    f[7] = __builtin_bit_cast(float, v.w & 0xFFFF0000u);
}
__device__ __forceinline__ uint4 pack8(const float* f) {
    uint4 o;
    o.x = f2bf_u(f[0]) | (f2bf_u(f[1]) << 16);
    o.y = f2bf_u(f[2]) | (f2bf_u(f[3]) << 16);
    o.z = f2bf_u(f[4]) | (f2bf_u(f[5]) << 16);
    o.w = f2bf_u(f[6]) | (f2bf_u(f[7]) << 16);
    return o;
}
// fp8 e4m3 decode: 8 bytes -> 8 floats (HW cvt, format-consistent with encode)
__device__ __forceinline__ void dec8(uint2 v, float* f) {
    f32x2 a0 = __builtin_amdgcn_cvt_pk_f32_fp8(v.x, false);
    f32x2 a1 = __builtin_amdgcn_cvt_pk_f32_fp8(v.x, true);
    f32x2 a2 = __builtin_amdgcn_cvt_pk_f32_fp8(v.y, false);
    f32x2 a3 = __builtin_amdgcn_cvt_pk_f32_fp8(v.y, true);
    f[0] = a0[0]; f[1] = a0[1]; f[2] = a1[0]; f[3] = a1[1];
    f[4] = a2[0]; f[5] = a2[1]; f[6] = a3[0]; f[7] = a3[1];
}

// ---- K0a: W_qkv[:, 0:1536] -> BPqk (q|k weights, frag-packed B^T)
__global__ void wqk_pack(const float* __restrict__ Wqkv, u16* __restrict__ BP) {
    int j = blockIdx.x * 32 + threadIdx.x;   // q|k col, 0..1535
    int c = blockIdx.y * 32 + threadIdx.y;   // K dim, 0..767
    BP[gpack(j, c)] = (u16)f2bf_u(Wqkv[(size_t)c * 2304 + j]);
}

// ---- K0b: BPo[gpack(c2,c)] = sum_e Wout[e][c2] * Wv[c][e]  ((W_v@W_out)^T, packed)
__global__ void wvo_gemm(const float* __restrict__ Wqkv, const float* __restrict__ Wout,
                         u16* __restrict__ BPo) {
    __shared__ float la[32][33];
    __shared__ float lb[32][33];
    int c0 = blockIdx.x * 32, c20 = blockIdx.y * 32;
    int tx = threadIdx.x, ty = threadIdx.y;
    float acc = 0.f;
    for (int e0 = 0; e0 < 768; e0 += 32) {
        la[ty][tx] = Wout[(size_t)(e0 + ty) * 768 + c20 + tx];
        lb[ty][tx] = Wqkv[(size_t)(c0 + ty) * 2304 + 1536 + e0 + tx];
        __syncthreads();
        #pragma unroll
        for (int e = 0; e < 32; ++e)
            acc = fmaf(la[e][ty], lb[tx][e], acc);
        __syncthreads();
    }
    BPo[gpack(c20 + ty, c0 + tx)] = (u16)f2bf_u(acc);
}

// ---- K0c: x fp32 -> xb bf16 in frag-packed layout (per-(b,t)-plane permutation)
__global__ __launch_bounds__(256)
void cvt_pack_x(const float* __restrict__ x, u16* __restrict__ xb) {
    const int g  = blockIdx.x;    // 0..63 row-group within plane
    const int bt = blockIdx.y;    // 0..143
    const float* src = x + (size_t)bt * PLANE;
    u16* dst = xb + (size_t)bt * PLANE + (size_t)g * 12288;
    #pragma unroll 1
    for (int s = threadIdx.x; s < 1536; s += 256) {
        int nl = s / 96, cc = s % 96;
        const float* sp = src + ((size_t)(g * 16 + nl)) * 768 + cc * 8;
        float f[8];
        f32x4 v0 = *(const f32x4*)sp;
        f32x4 v1 = *(const f32x4*)(sp + 4);
        f[0] = v0.x; f[1] = v0.y; f[2] = v0.z; f[3] = v0.w;
        f[4] = v1.x; f[5] = v1.y; f[6] = v1.z; f[7] = v1.w;
        int off = (cc >> 2) * 512 + (nl + 16 * (cc & 3)) * 8;
        *(uint4*)(dst + off) = pack8(f);
    }
}

// ---- 256x128-tile GEMM on frag-packed operands; A AND B via LDS.
// 512 thr = 8 waves (4M x 2N), wave-tile 64x64 (acc = 64 VGPR).
// BK=32, 3 buffers x 24KB = 72KB LDS -> 2 blocks/CU (TLP hides stalls).
// 3 gload_lds/thread/K-tile (contiguous 1KB slabs), counted vmcnt(3).
// WM==0: fp8-e4m3 C ; WM==1: f32 C + bias
template<int WM>
__global__ __launch_bounds__(512, 4)
void gemm256(const u16* __restrict__ A, const u16* __restrict__ BP,
             void* __restrict__ Cv, const float* __restrict__ bias, int N) {
    constexpr int KT = 24;                       // K-tiles of 32
    __shared__ __align__(16) u16 lds[3 * 12288]; // per buf: A 8192 + B 4096 u16
    const int tid  = threadIdx.x;
    const int lane = tid & 63;
    const int wid  = tid >> 6;
    const int wm   = wid >> 1;                // 0..3 (m quarter, 64 rows)
    const int wn   = wid & 1;                 // 0..1 (n half, 64 cols)
    const int nbx  = N >> 7;
    const int cpx  = (int)gridDim.x >> 3;
    const int bid  = (int)blockIdx.x;
    const int swzb = (bid & 7) * cpx + (bid >> 3);   // bijective XCD swizzle
    const int bx   = swzb % nbx, by = swzb / nbx;
    const long m0  = (long)by << 8;
    const long n0  = (long)bx << 7;
    const int  g0  = (int)(m0 >> 4);          // A row-group base (16 groups)
    const int  h0  = (int)(n0 >> 4);          // B row-group base (8 groups)

    // staging: wave w stages A slabs w, w+8 and B slab w (1KB each, contiguous)
    const u16* agp0 = A  + (size_t)(g0 + wid) * 12288 + lane * 8;
    const u16* agp1 = A  + (size_t)(g0 + wid + 8) * 12288 + lane * 8;
    const u16* bgp  = BP + (size_t)(h0 + wid) * 12288 + lane * 8;
    u16* adp0 = lds + wid * 512;              // wave-uniform; lane*16B implicit
    u16* adp1 = lds + (wid + 8) * 512;
    u16* bdp  = lds + 8192 + wid * 512;

    f32x4 acc[4][4] = {};

    #define STAGE(tt) { const int o_ = ((tt) % 3) * 12288; const int k_ = (tt) * 512; \
        GLOAD_LDS16(agp0 + k_, adp0 + o_); GLOAD_LDS16(agp1 + k_, adp1 + o_); \
        GLOAD_LDS16(bgp  + k_, bdp  + o_); }

    // prologue: tiles 0,1 in flight (6 loads); wait tile0 (leave tile1's 3)
    STAGE(0); STAGE(1);
    asm volatile("s_waitcnt vmcnt(3)" ::: "memory");
    __builtin_amdgcn_s_barrier();

    #pragma unroll 3
    for (int t = 0; t < KT; ++t) {
        const u16* lp = lds + (t % 3) * 12288;
        s16x8 af[4], bf[4];
        #pragma unroll
        for (int mi = 0; mi < 4; ++mi)
            af[mi] = *(const s16x8*)(lp + (wm * 4 + mi) * 512 + lane * 8);
        #pragma unroll
        for (int ni = 0; ni < 4; ++ni)
            bf[ni] = *(const s16x8*)(lp + 8192 + (wn * 4 + ni) * 512 + lane * 8);
        if (t + 2 < KT) STAGE(t + 2);
        __builtin_amdgcn_s_setprio(1);
        #pragma unroll
        for (int mi = 0; mi < 4; ++mi)
            #pragma unroll
            for (int ni = 0; ni < 4; ++ni)
                acc[mi][ni] = __builtin_amdgcn_mfma_f32_16x16x32_bf16(
                    af[mi], bf[ni], acc[mi][ni], 0, 0, 0);
        __builtin_amdgcn_s_setprio(0);
        // keep next tile's 3 loads in flight; guarantee tile t+1 resident
        if (t <= KT - 3)      { asm volatile("s_waitcnt vmcnt(3)" ::: "memory"); }
        else if (t == KT - 2) { asm volatile("s_waitcnt vmcnt(0)" ::: "memory"); }
        __builtin_amdgcn_s_barrier();
    }
    #undef STAGE

    // ---- epilogue (row-major C)
    const int crow = (lane >> 4) << 2;
    const int ccol = lane & 15;
    if constexpr (WM == 0) {
        u8* C = (u8*)Cv;   // fp8 e4m3
        #pragma unroll
        for (int mi = 0; mi < 4; ++mi)
            #pragma unroll
            for (int ni = 0; ni < 4; ++ni) {
                long r = m0 + wm * 64 + mi * 16 + crow;
                long c = n0 + wn * 64 + ni * 16 + ccol;
                #pragma unroll
                for (int i = 0; i < 4; ++i) {
                    unsigned pk = __builtin_amdgcn_cvt_pk_fp8_f32(
                        acc[mi][ni][i], acc[mi][ni][i], 0, false);
                    C[(r + i) * (long)N + c] = (u8)(pk & 0xFF);
                }
            }
    } else {
        float* C = (float*)Cv;
        #pragma unroll
        for (int mi = 0; mi < 4; ++mi)
            #pragma unroll
            for (int ni = 0; ni < 4; ++ni) {
                long r = m0 + wm * 64 + mi * 16 + crow;
                long c = n0 + wn * 64 + ni * 16 + ccol;
                float bv = bias[c];
                #pragma unroll
                for (int i = 0; i < 4; ++i)
                    C[(r + i) * (long)N + c] = acc[mi][ni][i] + bv;
            }
    }
}

// ---- K2: partial dots[b,h,t,s] over this block's (n,d)-chunk; QK is fp8 e4m3
__global__ __launch_bounds__(256)
void dots_partial(const u8* __restrict__ QK, float* __restrict__ part) {
    const int tid = threadIdx.x;
    const int ch  = blockIdx.x;   // 16 chunks
    const int h   = blockIdx.y;   // 8
    const int b   = blockIdx.z;   // 16
    const size_t tstride = (size_t)NN * NQK;  // bytes per t-plane
    const u8* base = QK + (size_t)b * 9 * tstride + h * NHD;

    float acc[9][9] = {};
    #pragma unroll 1
    for (int j = 0; j < 3; ++j) {
        int p  = ch * 768 + j * 256 + tid;   // 8B piece index, < 12288
        int n  = p / 12, dc = p % 12;
        const u8* qp = base + (size_t)n * NQK + dc * 8;
        float qf[9][8];
        #pragma unroll
        for (int t = 0; t < 9; ++t) {
            uint2 qv = *(const uint2*)(qp + (size_t)t * tstride);
            dec8(qv, qf[t]);
        }
        #pragma unroll
        for (int s = 0; s < 9; ++s) {
            uint2 kv = *(const uint2*)(qp + (size_t)s * tstride + 768);
            float kf[8]; dec8(kv, kf);
            #pragma unroll
            for (int t = 0; t < 9; ++t)
                #pragma unroll
                for (int e = 0; e < 8; ++e)
                    acc[t][s] = fmaf(qf[t][e], kf[e], acc[t][s]);
        }
    }
    #pragma unroll
    for (int t = 0; t < 9; ++t)
        #pragma unroll
        for (int s = 0; s < 9; ++s) {
            float v = acc[t][s];
            #pragma unroll
            for (int m = 1; m < 64; m <<= 1) v += __shfl_xor(v, m, 64);
            acc[t][s] = v;
        }
    __shared__ float red[4][81];
    if ((tid & 63) == 0) {
        #pragma unroll
        for (int t = 0; t < 9; ++t)
            #pragma unroll
            for (int s = 0; s < 9; ++s) red[tid >> 6][t * 9 + s] = acc[t][s];
    }
    __syncthreads();
    if (tid < 81) {
        float v = red[0][tid] + red[1][tid] + red[2][tid] + red[3][tid];
        part[((size_t)ch * 128 + b * 8 + h) * 81 + tid] = v;
    }
}

// ---- K3: sum partials -> scale -> softmax(s) -> mean(h) -> @W_temp + b_temp -> ta
__global__ void finalize_ta(const float* __restrict__ part, const float* __restrict__ Wtmp,
                            const float* __restrict__ btmp, float* __restrict__ ta) {
    const int b = blockIdx.x;
    const int tid = threadIdx.x;
    __shared__ float attn_l[8][9][9];
    if (tid < 72) {
        int h = tid / 9, t = tid % 9;
        float v[9];
        #pragma unroll
        for (int s = 0; s < 9; ++s) {
            float a = 0.f;
            for (int ch = 0; ch < 16; ++ch)
                a += part[((size_t)ch * 128 + b * 8 + h) * 81 + t * 9 + s];
            v[s] = a * (SCALE_F / 1024.0f);
        }
        float mx = v[0];
        #pragma unroll
        for (int s = 1; s < 9; ++s) mx = fmaxf(mx, v[s]);
        float den = 0.f;
        #pragma unroll
        for (int s = 0; s < 9; ++s) { v[s] = __expf(v[s] - mx); den += v[s]; }
        float inv = 1.0f / den;
        #pragma unroll
        for (int s = 0; s < 9; ++s) attn_l[h][t][s] = v[s] * inv;
    }
    __syncthreads();
    if (tid < 81) {
        int t = tid / 9, j = tid % 9;
        float o = btmp[j];
        #pragma unroll
        for (int s = 0; s < 9; ++s) {
            float am = 0.f;
            #pragma unroll
            for (int hh = 0; hh < 8; ++hh) am += attn_l[hh][t][s];
            o = fmaf(am * 0.125f, Wtmp[s * 9 + j], o);
        }
        ta[(size_t)b * 81 + t * 9 + j] = o;
    }
}

// ---- K4: in-place temporal mix (layout-agnostic across planes)
__global__ __launch_bounds__(256)
void tmix(u16* __restrict__ xb, const float* __restrict__ ta) {
    const int b = blockIdx.y;
    const int tid = threadIdx.x;
    __shared__ float tl[81];
    if (tid < 81) tl[tid] = ta[(size_t)b * 81 + tid];
    __syncthreads();
    size_t off = ((size_t)blockIdx.x * 256 + tid) * 8;
    u16* pb = xb + (size_t)b * 9 * PLANE + off;
    float acc[9][8] = {};
    #pragma unroll
    for (int s = 0; s < 9; ++s) {
        uint4 xv = *(const uint4*)(pb + (size_t)s * PLANE);
        float xf[8]; cvt8(xv, xf);
        #pragma unroll
        for (int t = 0; t < 9; ++t) {
            float w = tl[t * 9 + s];
            #pragma unroll
            for (int e = 0; e < 8; ++e) acc[t][e] = fmaf(w, xf[e], acc[t][e]);
        }
    }
    #pragma unroll
    for (int t = 0; t < 9; ++t)
        *(uint4*)(pb + (size_t)t * PLANE) = pack8(acc[t]);
}

extern "C" void kernel_launch(void* const* d_in, const int* in_sizes, int n_in,
                              void* d_out, int out_size, void* d_ws, size_t ws_size,
                              hipStream_t stream) {
    (void)in_sizes; (void)n_in; (void)out_size; (void)ws_size;
    const float* x    = (const float*)d_in[0];
    const float* Wqkv = (const float*)d_in[1];
    const float* Wtmp = (const float*)d_in[2];
    const float* btmp = (const float*)d_in[3];
    const float* Wout = (const float*)d_in[4];
    const float* bout = (const float*)d_in[5];

    char* ws = (char*)d_ws;
    u16*   xb   = (u16*)ws;                       // 226,492,416 B (frag-packed)
    u16*   BPqk = (u16*)(ws + 226492416ull);      //   2,359,296 B
    u16*   BPo  = (u16*)(ws + 228851712ull);      //   1,179,648 B
    float* part = (float*)(ws + 230031360ull);    //     663,552 B
    float* ta   = (float*)(ws + 230694912ull);    //       5,184 B
    u8*    QK8  = (u8*)d_out;                     // 226,492,416 B fp8 scratch in d_out
                                                  // (consumed by dots before gemm<1> overwrites)

    wqk_pack<<<dim3(48, 24), dim3(32, 32), 0, stream>>>(Wqkv, BPqk);
    wvo_gemm<<<dim3(24, 24), dim3(32, 32), 0, stream>>>(Wqkv, Wout, BPo);
    cvt_pack_x<<<dim3(64, 144), 256, 0, stream>>>(x, xb);
    gemm256<0><<<6912, 512, 0, stream>>>(xb, BPqk, (void*)QK8, nullptr, NQK);
    dots_partial<<<dim3(16, 8, 16), 256, 0, stream>>>(QK8, part);
    finalize_ta<<<16, 128, 0, stream>>>(part, Wtmp, btmp, ta);
    tmix<<<dim3(384, 16), 256, 0, stream>>>(xb, ta);
    gemm256<1><<<3456, 512, 0, stream>>>(xb, BPo, d_out, bout, NDIM);
}

// Round 7
// 1032.476 us; speedup vs baseline: 1.4472x; 1.4472x over previous
//
#include <hip/hip_runtime.h>
#include <stdint.h>

typedef unsigned short u16;
typedef unsigned char u8;
typedef float f32x4 __attribute__((ext_vector_type(4)));
typedef float f32x2 __attribute__((ext_vector_type(2)));
typedef float f32x16 __attribute__((ext_vector_type(16)));
typedef short s16x8 __attribute__((ext_vector_type(8)));

#define NB 16
#define NT 9
#define NN 1024
#define NDIM 768
#define NH 8
#define NHD 96
#define NM (NB*NT*NN)          // 147456 rows
#define NQK 1536               // q|k columns
#define PLANE (NN*NDIM)        // 786432 elems per (b,t) plane
#define SCALE_F 0.10206207261596575f   // 96^-0.5

typedef __attribute__((address_space(1))) const void gvoid_t;
typedef __attribute__((address_space(3))) void lvoid_t;
#define GLOAD_LDS16(gp, lp) __builtin_amdgcn_global_load_lds((gvoid_t*)(gp), (lvoid_t*)(lp), 16, 0, 0)

// Packed operand layout for 32x32x16 MFMA (K=768): matrix[row][col] at u16 idx
//   (row>>5)*24576 + (col>>4)*512 + ((row&31) + 32*((col>>3)&1))*8 + (col&7)
// = [row-group32][k-chunk16] slabs of 1KB; lane l reads its fragment at l*8
// (contiguous 1KB per fragment -> zero bank conflicts, linear gload_lds).
__device__ __forceinline__ size_t gpack32(int row, int col) {
    return (size_t)(row >> 5) * 24576 + ((col >> 4) * 512)
         + (((row & 31) + 32 * ((col >> 3) & 1)) * 8) + (col & 7);
}

__device__ __forceinline__ unsigned f2bf_u(float x) {
    unsigned u = __builtin_bit_cast(unsigned, x);
    return (u + 0x7FFFu + ((u >> 16) & 1u)) >> 16;   // RNE
}
__device__ __forceinline__ void cvt8(uint4 v, float* f) {
    f[0] = __builtin_bit_cast(float, v.x << 16);
    f[1] = __builtin_bit_cast(float, v.x & 0xFFFF0000u);
    f[2] = __builtin_bit_cast(float, v.y << 16);
    f[3] = __builtin_bit_cast(float, v.y & 0xFFFF0000u);
    f[4] = __builtin_bit_cast(float, v.z << 16);
    f[5] = __builtin_bit_cast(float, v.z & 0xFFFF0000u);
    f[6] = __builtin_bit_cast(float, v.w << 16);
    f[7] = __builtin_bit_cast(float, v.w & 0xFFFF0000u);
}
__device__ __forceinline__ uint4 pack8(const float* f) {
    uint4 o;
    o.x = f2bf_u(f[0]) | (f2bf_u(f[1]) << 16);
    o.y = f2bf_u(f[2]) | (f2bf_u(f[3]) << 16);
    o.z = f2bf_u(f[4]) | (f2bf_u(f[5]) << 16);
    o.w = f2bf_u(f[6]) | (f2bf_u(f[7]) << 16);
    return o;
}
// fp8 e4m3 decode: 8 bytes -> 8 floats (HW cvt, format-consistent with encode)
__device__ __forceinline__ void dec8(uint2 v, float* f) {
    f32x2 a0 = __builtin_amdgcn_cvt_pk_f32_fp8(v.x, false);
    f32x2 a1 = __builtin_amdgcn_cvt_pk_f32_fp8(v.x, true);
    f32x2 a2 = __builtin_amdgcn_cvt_pk_f32_fp8(v.y, false);
    f32x2 a3 = __builtin_amdgcn_cvt_pk_f32_fp8(v.y, true);
    f[0] = a0[0]; f[1] = a0[1]; f[2] = a1[0]; f[3] = a1[1];
    f[4] = a2[0]; f[5] = a2[1]; f[6] = a3[0]; f[7] = a3[1];
}

// ---- K0a: W_qkv[:, 0:1536] -> BPqk (q|k weights, frag-packed B^T, 48 groups)
__global__ void wqk_pack(const float* __restrict__ Wqkv, u16* __restrict__ BP) {
    int j = blockIdx.x * 32 + threadIdx.x;   // q|k col, 0..1535
    int c = blockIdx.y * 32 + threadIdx.y;   // K dim, 0..767
    BP[gpack32(j, c)] = (u16)f2bf_u(Wqkv[(size_t)c * 2304 + j]);
}

// ---- K0b: BPo[gpack32(c2,c)] = sum_e Wout[e][c2] * Wv[c][e]  ((W_v@W_out)^T, packed)
__global__ void wvo_gemm(const float* __restrict__ Wqkv, const float* __restrict__ Wout,
                         u16* __restrict__ BPo) {
    __shared__ float la[32][33];
    __shared__ float lb[32][33];
    int c0 = blockIdx.x * 32, c20 = blockIdx.y * 32;
    int tx = threadIdx.x, ty = threadIdx.y;
    float acc = 0.f;
    for (int e0 = 0; e0 < 768; e0 += 32) {
        la[ty][tx] = Wout[(size_t)(e0 + ty) * 768 + c20 + tx];
        lb[ty][tx] = Wqkv[(size_t)(c0 + ty) * 2304 + 1536 + e0 + tx];
        __syncthreads();
        #pragma unroll
        for (int e = 0; e < 32; ++e)
            acc = fmaf(la[e][ty], lb[tx][e], acc);
        __syncthreads();
    }
    BPo[gpack32(c20 + ty, c0 + tx)] = (u16)f2bf_u(acc);
}

// ---- K0c: x fp32 -> xb bf16 in 32-group frag-packed layout (per-plane permutation)
__global__ __launch_bounds__(256)
void cvt_pack_x(const float* __restrict__ x, u16* __restrict__ xb) {
    const int g  = blockIdx.x;    // 0..31 row-group within plane
    const int bt = blockIdx.y;    // 0..143
    const float* src = x + (size_t)bt * PLANE;
    u16* dst = xb + (size_t)bt * PLANE + (size_t)g * 24576;
    #pragma unroll 1
    for (int s = threadIdx.x; s < 3072; s += 256) {
        int nl = s / 96, cc = s % 96;   // row-local 0..31, col-chunk-of-8 0..95
        const float* sp = src + ((size_t)(g * 32 + nl)) * 768 + cc * 8;
        float f[8];
        f32x4 v0 = *(const f32x4*)sp;
        f32x4 v1 = *(const f32x4*)(sp + 4);
        f[0] = v0.x; f[1] = v0.y; f[2] = v0.z; f[3] = v0.w;
        f[4] = v1.x; f[5] = v1.y; f[6] = v1.z; f[7] = v1.w;
        int off = (cc >> 1) * 512 + (nl + 32 * (cc & 1)) * 8;
        *(uint4*)(dst + off) = pack8(f);
    }
}

// ---- 256x256-tile GEMM, 32x32x16 MFMA, frag-packed operands, both via LDS.
// 512 thr = 8 waves (2M x 4N), wave-tile 128x64: acc = 4x2 f32x16 (128 VGPR).
// BK=32, 4 bufs x 32KB = 128KB LDS (1 block/CU). Zero-conflict 1KB-slab reads,
// counted vmcnt(8/4/0), raw s_barrier, setprio around the 16-MFMA cluster.
// WM==0: fp8-e4m3 C ; WM==1: f32 C + bias
template<int WM>
__global__ __launch_bounds__(512, 2)
void gemm256(const u16* __restrict__ A, const u16* __restrict__ BP,
             void* __restrict__ Cv, const float* __restrict__ bias, int N) {
    constexpr int KT = 24;                     // K-tiles of 32
    __shared__ __align__(16) u16 lds[4 * 16384];  // 4 bufs x (A 16KB + B 16KB)
    const int tid  = threadIdx.x;
    const int lane = tid & 63;
    const int wid  = tid >> 6;
    const int wr   = wid >> 2;                 // 0..1 (m-half: 128 rows)
    const int wc   = wid & 3;                  // 0..3 (n-quarter: 64 cols)
    const int nbx  = N >> 8;
    const int cpx  = (int)gridDim.x >> 3;
    const int bid  = (int)blockIdx.x;
    const int swzb = (bid & 7) * cpx + (bid >> 3);   // bijective XCD swizzle
    const int bx   = swzb % nbx, by = swzb / nbx;
    const long m0  = (long)by << 8;
    const long n0  = (long)bx << 8;

    // staging: wave w stages A row-group (m0>>5)+w and B row-group (n0>>5)+w;
    // per K-tile that's 2 contiguous 1KB slabs each (k-chunks 2t, 2t+1).
    const u16* ag = A  + (size_t)((m0 >> 5) + wid) * 24576 + lane * 8;
    const u16* bg = BP + (size_t)((n0 >> 5) + wid) * 24576 + lane * 8;
    u16* adst = lds + wid * 1024;              // wave-uniform; lane*16B implicit
    u16* bdst = lds + 8192 + wid * 1024;

    // fragment read base (lane-contiguous slabs)
    const u16* lbase = lds + lane * 8;

    f32x16 acc[4][2] = {};

    #define STAGE(tt) { const int o_ = ((tt) & 3) * 16384; const int k_ = (tt) * 1024; \
        GLOAD_LDS16(ag + k_,       adst + o_);       \
        GLOAD_LDS16(ag + k_ + 512, adst + o_ + 512); \
        GLOAD_LDS16(bg + k_,       bdst + o_);       \
        GLOAD_LDS16(bg + k_ + 512, bdst + o_ + 512); }

    // prologue: tiles 0,1,2 in flight (12 loads); retire through tile0
    STAGE(0); STAGE(1); STAGE(2);
    asm volatile("s_waitcnt vmcnt(8)" ::: "memory");
    __builtin_amdgcn_s_barrier();

    #pragma unroll 4
    for (int t = 0; t < KT; ++t) {
        const u16* lp = lbase + (t & 3) * 16384;
        s16x8 af[4][2], bf[2][2];
        #pragma unroll
        for (int mi = 0; mi < 4; ++mi)
            #pragma unroll
            for (int c = 0; c < 2; ++c)
                af[mi][c] = *(const s16x8*)(lp + ((wr * 4 + mi) * 2 + c) * 512);
        #pragma unroll
        for (int ni = 0; ni < 2; ++ni)
            #pragma unroll
            for (int c = 0; c < 2; ++c)
                bf[ni][c] = *(const s16x8*)(lp + 8192 + ((wc * 2 + ni) * 2 + c) * 512);
        if (t + 3 < KT) STAGE(t + 3);
        __builtin_amdgcn_s_setprio(1);
        #pragma unroll
        for (int c = 0; c < 2; ++c)
            #pragma unroll
            for (int mi = 0; mi < 4; ++mi)
                #pragma unroll
                for (int ni = 0; ni < 2; ++ni)
                    acc[mi][ni] = __builtin_amdgcn_mfma_f32_32x32x16_bf16(
                        af[mi][c], bf[ni][c], acc[mi][ni], 0, 0, 0);
        __builtin_amdgcn_s_setprio(0);
        // counted wait: tile t+1 (staged at iter t-2) fully resident
        if (t < KT - 3)       { asm volatile("s_waitcnt vmcnt(8)" ::: "memory"); }
        else if (t == KT - 3) { asm volatile("s_waitcnt vmcnt(4)" ::: "memory"); }
        else if (t == KT - 2) { asm volatile("s_waitcnt vmcnt(0)" ::: "memory"); }
        __builtin_amdgcn_s_barrier();
    }
    #undef STAGE

    // ---- epilogue: C/D layout (32x32): col = lane&31, row = (r&3)+8*(r>>2)+4*(lane>>5)
    const int cl = lane & 31;
    const int lh = lane >> 5;
    if constexpr (WM == 0) {
        u8* C = (u8*)Cv;   // fp8 e4m3
        #pragma unroll
        for (int mi = 0; mi < 4; ++mi)
            #pragma unroll
            for (int ni = 0; ni < 2; ++ni) {
                long rbase = m0 + (wr * 4 + mi) * 32 + 4 * lh;
                long c = n0 + (wc * 2 + ni) * 32 + cl;
                #pragma unroll
                for (int r = 0; r < 16; ++r) {
                    long row = rbase + (r & 3) + 8 * (r >> 2);
                    unsigned pk = __builtin_amdgcn_cvt_pk_fp8_f32(
                        acc[mi][ni][r], acc[mi][ni][r], 0, false);
                    C[row * (long)N + c] = (u8)(pk & 0xFF);
                }
            }
    } else {
        float* C = (float*)Cv;
        #pragma unroll
        for (int mi = 0; mi < 4; ++mi)
            #pragma unroll
            for (int ni = 0; ni < 2; ++ni) {
                long rbase = m0 + (wr * 4 + mi) * 32 + 4 * lh;
                long c = n0 + (wc * 2 + ni) * 32 + cl;
                float bv = bias[c];
                #pragma unroll
                for (int r = 0; r < 16; ++r) {
                    long row = rbase + (r & 3) + 8 * (r >> 2);
                    C[row * (long)N + c] = acc[mi][ni][r] + bv;
                }
            }
    }
}

// ---- K2: partial dots[b,h,t,s] over this block's (n,d)-chunk; QK is fp8 e4m3
__global__ __launch_bounds__(256)
void dots_partial(const u8* __restrict__ QK, float* __restrict__ part) {
    const int tid = threadIdx.x;
    const int ch  = blockIdx.x;   // 16 chunks
    const int h   = blockIdx.y;   // 8
    const int b   = blockIdx.z;   // 16
    const size_t tstride = (size_t)NN * NQK;  // bytes per t-plane
    const u8* base = QK + (size_t)b * 9 * tstride + h * NHD;

    float acc[9][9] = {};
    #pragma unroll 1
    for (int j = 0; j < 3; ++j) {
        int p  = ch * 768 + j * 256 + tid;   // 8B piece index, < 12288
        int n  = p / 12, dc = p % 12;
        const u8* qp = base + (size_t)n * NQK + dc * 8;
        float qf[9][8];
        #pragma unroll
        for (int t = 0; t < 9; ++t) {
            uint2 qv = *(const uint2*)(qp + (size_t)t * tstride);
            dec8(qv, qf[t]);
        }
        #pragma unroll
        for (int s = 0; s < 9; ++s) {
            uint2 kv = *(const uint2*)(qp + (size_t)s * tstride + 768);
            float kf[8]; dec8(kv, kf);
            #pragma unroll
            for (int t = 0; t < 9; ++t)
                #pragma unroll
                for (int e = 0; e < 8; ++e)
                    acc[t][s] = fmaf(qf[t][e], kf[e], acc[t][s]);
        }
    }
    #pragma unroll
    for (int t = 0; t < 9; ++t)
        #pragma unroll
        for (int s = 0; s < 9; ++s) {
            float v = acc[t][s];
            #pragma unroll
            for (int m = 1; m < 64; m <<= 1) v += __shfl_xor(v, m, 64);
            acc[t][s] = v;
        }
    __shared__ float red[4][81];
    if ((tid & 63) == 0) {
        #pragma unroll
        for (int t = 0; t < 9; ++t)
            #pragma unroll
            for (int s = 0; s < 9; ++s) red[tid >> 6][t * 9 + s] = acc[t][s];
    }
    __syncthreads();
    if (tid < 81) {
        float v = red[0][tid] + red[1][tid] + red[2][tid] + red[3][tid];
        part[((size_t)ch * 128 + b * 8 + h) * 81 + tid] = v;
    }
}

// ---- K3: sum partials -> scale -> softmax(s) -> mean(h) -> @W_temp + b_temp -> ta
__global__ void finalize_ta(const float* __restrict__ part, const float* __restrict__ Wtmp,
                            const float* __restrict__ btmp, float* __restrict__ ta) {
    const int b = blockIdx.x;
    const int tid = threadIdx.x;
    __shared__ float attn_l[8][9][9];
    if (tid < 72) {
        int h = tid / 9, t = tid % 9;
        float v[9];
        #pragma unroll
        for (int s = 0; s < 9; ++s) {
            float a = 0.f;
            for (int ch = 0; ch < 16; ++ch)
                a += part[((size_t)ch * 128 + b * 8 + h) * 81 + t * 9 + s];
            v[s] = a * (SCALE_F / 1024.0f);
        }
        float mx = v[0];
        #pragma unroll
        for (int s = 1; s < 9; ++s) mx = fmaxf(mx, v[s]);
        float den = 0.f;
        #pragma unroll
        for (int s = 0; s < 9; ++s) { v[s] = __expf(v[s] - mx); den += v[s]; }
        float inv = 1.0f / den;
        #pragma unroll
        for (int s = 0; s < 9; ++s) attn_l[h][t][s] = v[s] * inv;
    }
    __syncthreads();
    if (tid < 81) {
        int t = tid / 9, j = tid % 9;
        float o = btmp[j];
        #pragma unroll
        for (int s = 0; s < 9; ++s) {
            float am = 0.f;
            #pragma unroll
            for (int hh = 0; hh < 8; ++hh) am += attn_l[hh][t][s];
            o = fmaf(am * 0.125f, Wtmp[s * 9 + j], o);
        }
        ta[(size_t)b * 81 + t * 9 + j] = o;
    }
}

// ---- K4: in-place temporal mix (layout-agnostic: packing is per-plane permutation)
__global__ __launch_bounds__(256)
void tmix(u16* __restrict__ xb, const float* __restrict__ ta) {
    const int b = blockIdx.y;
    const int tid = threadIdx.x;
    __shared__ float tl[81];
    if (tid < 81) tl[tid] = ta[(size_t)b * 81 + tid];
    __syncthreads();
    size_t off = ((size_t)blockIdx.x * 256 + tid) * 8;
    u16* pb = xb + (size_t)b * 9 * PLANE + off;
    float acc[9][8] = {};
    #pragma unroll
    for (int s = 0; s < 9; ++s) {
        uint4 xv = *(const uint4*)(pb + (size_t)s * PLANE);
        float xf[8]; cvt8(xv, xf);
        #pragma unroll
        for (int t = 0; t < 9; ++t) {
            float w = tl[t * 9 + s];
            #pragma unroll
            for (int e = 0; e < 8; ++e) acc[t][e] = fmaf(w, xf[e], acc[t][e]);
        }
    }
    #pragma unroll
    for (int t = 0; t < 9; ++t)
        *(uint4*)(pb + (size_t)t * PLANE) = pack8(acc[t]);
}

extern "C" void kernel_launch(void* const* d_in, const int* in_sizes, int n_in,
                              void* d_out, int out_size, void* d_ws, size_t ws_size,
                              hipStream_t stream) {
    (void)in_sizes; (void)n_in; (void)out_size; (void)ws_size;
    const float* x    = (const float*)d_in[0];
    const float* Wqkv = (const float*)d_in[1];
    const float* Wtmp = (const float*)d_in[2];
    const float* btmp = (const float*)d_in[3];
    const float* Wout = (const float*)d_in[4];
    const float* bout = (const float*)d_in[5];

    char* ws = (char*)d_ws;
    u16*   xb   = (u16*)ws;                       // 226,492,416 B (frag-packed)
    u16*   BPqk = (u16*)(ws + 226492416ull);      //   2,359,296 B
    u16*   BPo  = (u16*)(ws + 228851712ull);      //   1,179,648 B
    float* part = (float*)(ws + 230031360ull);    //     663,552 B
    float* ta   = (float*)(ws + 230694912ull);    //       5,184 B
    u8*    QK8  = (u8*)d_out;                     // 226,492,416 B fp8 scratch in d_out
                                                  // (consumed by dots before gemm<1> overwrites)

    wqk_pack<<<dim3(48, 24), dim3(32, 32), 0, stream>>>(Wqkv, BPqk);
    wvo_gemm<<<dim3(24, 24), dim3(32, 32), 0, stream>>>(Wqkv, Wout, BPo);
    cvt_pack_x<<<dim3(32, 144), 256, 0, stream>>>(x, xb);
    gemm256<0><<<3456, 512, 0, stream>>>(xb, BPqk, (void*)QK8, nullptr, NQK);
    dots_partial<<<dim3(16, 8, 16), 256, 0, stream>>>(QK8, part);
    finalize_ta<<<16, 128, 0, stream>>>(part, Wtmp, btmp, ta);
    tmix<<<dim3(384, 16), 256, 0, stream>>>(xb, ta);
    gemm256<1><<<1728, 512, 0, stream>>>(xb, BPo, d_out, bout, NDIM);
}

// Round 10
// 1028.127 us; speedup vs baseline: 1.4534x; 1.0042x over previous
//
#include <hip/hip_runtime.h>
#include <stdint.h>

typedef unsigned short u16;
typedef unsigned char u8;
typedef float f32x4 __attribute__((ext_vector_type(4)));
typedef float f32x2 __attribute__((ext_vector_type(2)));
typedef float f32x16 __attribute__((ext_vector_type(16)));
typedef short s16x8 __attribute__((ext_vector_type(8)));

#define NB 16
#define NT 9
#define NN 1024
#define NDIM 768
#define NH 8
#define NHD 96
#define NM (NB*NT*NN)          // 147456 rows
#define NQK 1536               // q|k columns
#define PLANE (NN*NDIM)        // 786432 elems per (b,t) plane
#define SCALE_F 0.10206207261596575f   // 96^-0.5

typedef __attribute__((address_space(1))) const void gvoid_t;
typedef __attribute__((address_space(3))) void lvoid_t;
#define GLOAD_LDS16(gp, lp) __builtin_amdgcn_global_load_lds((gvoid_t*)(gp), (lvoid_t*)(lp), 16, 0, 0)

// Packed operand layout for 32x32x16 MFMA (K=768): matrix[row][col] at u16 idx
//   (row>>5)*24576 + (col>>4)*512 + ((row&31) + 32*((col>>3)&1))*8 + (col&7)
// = [row-group32][k-chunk16] slabs of 1KB; lane l reads its fragment at l*8.
__device__ __forceinline__ size_t gpack32(int row, int col) {
    return (size_t)(row >> 5) * 24576 + ((col >> 4) * 512)
         + (((row & 31) + 32 * ((col >> 3) & 1)) * 8) + (col & 7);
}

__device__ __forceinline__ unsigned f2bf_u(float x) {
    unsigned u = __builtin_bit_cast(unsigned, x);
    return (u + 0x7FFFu + ((u >> 16) & 1u)) >> 16;   // RNE
}
__device__ __forceinline__ void cvt8(uint4 v, float* f) {
    f[0] = __builtin_bit_cast(float, v.x << 16);
    f[1] = __builtin_bit_cast(float, v.x & 0xFFFF0000u);
    f[2] = __builtin_bit_cast(float, v.y << 16);
    f[3] = __builtin_bit_cast(float, v.y & 0xFFFF0000u);
    f[4] = __builtin_bit_cast(float, v.z << 16);
    f[5] = __builtin_bit_cast(float, v.z & 0xFFFF0000u);
    f[6] = __builtin_bit_cast(float, v.w << 16);
    f[7] = __builtin_bit_cast(float, v.w & 0xFFFF0000u);
}
__device__ __forceinline__ uint4 pack8(const float* f) {
    uint4 o;
    o.x = f2bf_u(f[0]) | (f2bf_u(f[1]) << 16);
    o.y = f2bf_u(f[2]) | (f2bf_u(f[3]) << 16);
    o.z = f2bf_u(f[4]) | (f2bf_u(f[5]) << 16);
    o.w = f2bf_u(f[6]) | (f2bf_u(f[7]) << 16);
    return o;
}
// fp8 e4m3 decode: 8 bytes -> 8 floats (HW cvt, format-consistent with encode)
__device__ __forceinline__ void dec8(uint2 v, float* f) {
    f32x2 a0 = __builtin_amdgcn_cvt_pk_f32_fp8(v.x, false);
    f32x2 a1 = __builtin_amdgcn_cvt_pk_f32_fp8(v.x, true);
    f32x2 a2 = __builtin_amdgcn_cvt_pk_f32_fp8(v.y, false);
    f32x2 a3 = __builtin_amdgcn_cvt_pk_f32_fp8(v.y, true);
    f[0] = a0[0]; f[1] = a0[1]; f[2] = a1[0]; f[3] = a1[1];
    f[4] = a2[0]; f[5] = a2[1]; f[6] = a3[0]; f[7] = a3[1];
}

// ---- K0a: W_qkv[:, 0:1536] -> BPqk (q|k weights, frag-packed B^T)
__global__ void wqk_pack(const float* __restrict__ Wqkv, u16* __restrict__ BP) {
    int j = blockIdx.x * 32 + threadIdx.x;   // q|k col, 0..1535
    int c = blockIdx.y * 32 + threadIdx.y;   // K dim, 0..767
    BP[gpack32(j, c)] = (u16)f2bf_u(Wqkv[(size_t)c * 2304 + j]);
}

// ---- K0b: BPo[gpack32(c2,c)] = sum_e Wout[e][c2] * Wv[c][e]  ((W_v@W_out)^T, packed)
__global__ void wvo_gemm(const float* __restrict__ Wqkv, const float* __restrict__ Wout,
                         u16* __restrict__ BPo) {
    __shared__ float la[32][33];
    __shared__ float lb[32][33];
    int c0 = blockIdx.x * 32, c20 = blockIdx.y * 32;
    int tx = threadIdx.x, ty = threadIdx.y;
    float acc = 0.f;
    for (int e0 = 0; e0 < 768; e0 += 32) {
        la[ty][tx] = Wout[(size_t)(e0 + ty) * 768 + c20 + tx];
        lb[ty][tx] = Wqkv[(size_t)(c0 + ty) * 2304 + 1536 + e0 + tx];
        __syncthreads();
        #pragma unroll
        for (int e = 0; e < 32; ++e)
            acc = fmaf(la[e][ty], lb[tx][e], acc);
        __syncthreads();
    }
    BPo[gpack32(c20 + ty, c0 + tx)] = (u16)f2bf_u(acc);
}

// ---- K0c: x fp32 -> xb bf16 in 32-group frag-packed layout
__global__ __launch_bounds__(256)
void cvt_pack_x(const float* __restrict__ x, u16* __restrict__ xb) {
    const int g  = blockIdx.x;    // 0..31 row-group within plane
    const int bt = blockIdx.y;    // 0..143
    const float* src = x + (size_t)bt * PLANE;
    u16* dst = xb + (size_t)bt * PLANE + (size_t)g * 24576;
    #pragma unroll 1
    for (int s = threadIdx.x; s < 3072; s += 256) {
        int nl = s / 96, cc = s % 96;   // row-local 0..31, col-chunk-of-8 0..95
        const float* sp = src + ((size_t)(g * 32 + nl)) * 768 + cc * 8;
        float f[8];
        f32x4 v0 = *(const f32x4*)sp;
        f32x4 v1 = *(const f32x4*)(sp + 4);
        f[0] = v0.x; f[1] = v0.y; f[2] = v0.z; f[3] = v0.w;
        f[4] = v1.x; f[5] = v1.y; f[6] = v1.z; f[7] = v1.w;
        int off = (cc >> 1) * 512 + (nl + 32 * (cc & 1)) * 8;
        *(uint4*)(dst + off) = pack8(f);
    }
}

// ---- 256x256-tile GEMM, 32x32x16 MFMA, frag-packed, both operands via LDS.
// 512 thr = 8 waves (2M x 4N), wave-tile 128x64. BK=32 split into two c-steps
// of 8 MFMA; ds_reads for step s+1 issue BEFORE MFMA(s) (a0/b0 <-> a1/b1
// double-buffered regs) so LDS reads overlap the MFMA pipe. 4 LDS bufs.
// Prologue waits vmcnt(4): STAGE(0) AND STAGE(1) drained, because iter 0
// prefetches buffer-1 fragments mid-iteration (R8/R9 bug: vmcnt(8) left
// STAGE(1) in flight -> iter-0 read unwritten LDS).
// WM==0: fp8-e4m3 C ; WM==1: f32 C + bias
template<int WM>
__global__ __launch_bounds__(512, 2)
void gemm256(const u16* __restrict__ A, const u16* __restrict__ BP,
             void* __restrict__ Cv, const float* __restrict__ bias, int N) {
    constexpr int KT = 24;                     // K-tiles of 32
    __shared__ __align__(16) u16 lds[4 * 16384];  // 4 bufs x (A 16KB + B 16KB)
    const int tid  = threadIdx.x;
    const int lane = tid & 63;
    const int wid  = tid >> 6;
    const int wr   = wid >> 2;                 // 0..1 (m-half: 128 rows)
    const int wc   = wid & 3;                  // 0..3 (n-quarter: 64 cols)
    const int nbx  = N >> 8;
    const int cpx  = (int)gridDim.x >> 3;
    const int bid  = (int)blockIdx.x;
    const int swzb = (bid & 7) * cpx + (bid >> 3);   // bijective XCD swizzle
    const int bx   = swzb % nbx, by = swzb / nbx;
    const long m0  = (long)by << 8;
    const long n0  = (long)bx << 8;

    const u16* ag = A  + (size_t)((m0 >> 5) + wid) * 24576 + lane * 8;
    const u16* bg = BP + (size_t)((n0 >> 5) + wid) * 24576 + lane * 8;
    u16* adst = lds + wid * 1024;              // wave-uniform; lane*16B implicit
    u16* bdst = lds + 8192 + wid * 1024;
    const u16* lbase = lds + lane * 8;

    f32x16 acc[4][2] = {};
    s16x8 a0[4], b0[2], a1[4], b1[2];

    #define STAGE(tt) { const int o_ = ((tt) & 3) * 16384; const int k_ = (tt) * 1024; \
        GLOAD_LDS16(ag + k_,       adst + o_);       \
        GLOAD_LDS16(ag + k_ + 512, adst + o_ + 512); \
        GLOAD_LDS16(bg + k_,       bdst + o_);       \
        GLOAD_LDS16(bg + k_ + 512, bdst + o_ + 512); }
    #define LDFRAG(dA, dB, tt, cc) { \
        const u16* lp_ = lbase + ((tt) & 3) * 16384 + (cc) * 512; \
        _Pragma("unroll") \
        for (int mi = 0; mi < 4; ++mi) dA[mi] = *(const s16x8*)(lp_ + (wr * 4 + mi) * 1024); \
        _Pragma("unroll") \
        for (int ni = 0; ni < 2; ++ni) dB[ni] = *(const s16x8*)(lp_ + 8192 + (wc * 2 + ni) * 1024); }
    #define MFMA8(aa, bb) { \
        _Pragma("unroll") \
        for (int mi = 0; mi < 4; ++mi) \
            _Pragma("unroll") \
            for (int ni = 0; ni < 2; ++ni) \
                acc[mi][ni] = __builtin_amdgcn_mfma_f32_32x32x16_bf16(aa[mi], bb[ni], acc[mi][ni], 0, 0, 0); }

    STAGE(0); STAGE(1); STAGE(2);
    // Drain STAGE(0) AND STAGE(1): iter 0's mid-iteration LDFRAG(a0,b0,1,0)
    // reads buffer 1. (THE R8/R9 FIX: was vmcnt(8).)
    asm volatile("s_waitcnt vmcnt(4)" ::: "memory");
    __builtin_amdgcn_s_barrier();
    LDFRAG(a0, b0, 0, 0);

    #pragma unroll 4
    for (int t = 0; t < KT; ++t) {
        LDFRAG(a1, b1, t, 1);                  // frags for step c=1 (fly under MFMA)
        __builtin_amdgcn_s_setprio(1);
        MFMA8(a0, b0);                         // c=0 of tile t
        __builtin_amdgcn_s_setprio(0);
        if (t + 1 < KT) LDFRAG(a0, b0, t + 1, 0);  // frags for next tile's c=0
        if (t + 3 < KT) STAGE(t + 3);
        __builtin_amdgcn_s_setprio(1);
        MFMA8(a1, b1);                         // c=1 of tile t
        __builtin_amdgcn_s_setprio(0);
        // STAGE(t+2) forced complete (needed mid-iter t+1); STAGE(t+3) in flight
        if (t < KT - 3)       { asm volatile("s_waitcnt vmcnt(4)" ::: "memory"); }
        else if (t == KT - 3) { asm volatile("s_waitcnt vmcnt(0)" ::: "memory"); }
        __builtin_amdgcn_s_barrier();
    }
    #undef STAGE
    #undef LDFRAG
    #undef MFMA8

    // ---- epilogue: C/D 32x32: col = lane&31, row = (r&3)+8*(r>>2)+4*(lane>>5)
    const int cl = lane & 31;
    const int lh = lane >> 5;
    if constexpr (WM == 0) {
        u8* C = (u8*)Cv;   // fp8 e4m3
        #pragma unroll
        for (int mi = 0; mi < 4; ++mi)
            #pragma unroll
            for (int ni = 0; ni < 2; ++ni) {
                long rbase = m0 + (wr * 4 + mi) * 32 + 4 * lh;
                long c = n0 + (wc * 2 + ni) * 32 + cl;
                #pragma unroll
                for (int r = 0; r < 16; ++r) {
                    long row = rbase + (r & 3) + 8 * (r >> 2);
                    unsigned pk = __builtin_amdgcn_cvt_pk_fp8_f32(
                        acc[mi][ni][r], acc[mi][ni][r], 0, false);
                    C[row * (long)N + c] = (u8)(pk & 0xFF);
                }
            }
    } else {
        float* C = (float*)Cv;
        #pragma unroll
        for (int mi = 0; mi < 4; ++mi)
            #pragma unroll
            for (int ni = 0; ni < 2; ++ni) {
                long rbase = m0 + (wr * 4 + mi) * 32 + 4 * lh;
                long c = n0 + (wc * 2 + ni) * 32 + cl;
                float bv = bias[c];
                #pragma unroll
                for (int r = 0; r < 16; ++r) {
                    long row = rbase + (r & 3) + 8 * (r >> 2);
                    C[row * (long)N + c] = acc[mi][ni][r] + bv;
                }
            }
    }
}

// ---- K2: partial dots[b,h,t,s] over this block's (n,d)-chunk; QK is fp8 e4m3
__global__ __launch_bounds__(256)
void dots_partial(const u8* __restrict__ QK, float* __restrict__ part) {
    const int tid = threadIdx.x;
    const int ch  = blockIdx.x;   // 16 chunks
    const int h   = blockIdx.y;   // 8
    const int b   = blockIdx.z;   // 16
    const size_t tstride = (size_t)NN * NQK;  // bytes per t-plane
    const u8* base = QK + (size_t)b * 9 * tstride + h * NHD;

    float acc[9][9] = {};
    #pragma unroll 1
    for (int j = 0; j < 3; ++j) {
        int p  = ch * 768 + j * 256 + tid;   // 8B piece index, < 12288
        int n  = p / 12, dc = p % 12;
        const u8* qp = base + (size_t)n * NQK + dc * 8;
        float qf[9][8];
        #pragma unroll
        for (int t = 0; t < 9; ++t) {
            uint2 qv = *(const uint2*)(qp + (size_t)t * tstride);
            dec8(qv, qf[t]);
        }
        #pragma unroll
        for (int s = 0; s < 9; ++s) {
            uint2 kv = *(const uint2*)(qp + (size_t)s * tstride + 768);
            float kf[8]; dec8(kv, kf);
            #pragma unroll
            for (int t = 0; t < 9; ++t)
                #pragma unroll
                for (int e = 0; e < 8; ++e)
                    acc[t][s] = fmaf(qf[t][e], kf[e], acc[t][s]);
        }
    }
    #pragma unroll
    for (int t = 0; t < 9; ++t)
        #pragma unroll
        for (int s = 0; s < 9; ++s) {
            float v = acc[t][s];
            #pragma unroll
            for (int m = 1; m < 64; m <<= 1) v += __shfl_xor(v, m, 64);
            acc[t][s] = v;
        }
    __shared__ float red[4][81];
    if ((tid & 63) == 0) {
        #pragma unroll
        for (int t = 0; t < 9; ++t)
            #pragma unroll
            for (int s = 0; s < 9; ++s) red[tid >> 6][t * 9 + s] = acc[t][s];
    }
    __syncthreads();
    if (tid < 81) {
        float v = red[0][tid] + red[1][tid] + red[2][tid] + red[3][tid];
        part[((size_t)ch * 128 + b * 8 + h) * 81 + tid] = v;
    }
}

// ---- K3: sum partials -> scale -> softmax(s) -> mean(h) -> @W_temp + b -> ta
__global__ void finalize_ta(const float* __restrict__ part, const float* __restrict__ Wtmp,
                            const float* __restrict__ btmp, float* __restrict__ ta) {
    const int b = blockIdx.x;
    const int tid = threadIdx.x;
    __shared__ float attn_l[8][9][9];
    if (tid < 72) {
        int h = tid / 9, t = tid % 9;
        float v[9];
        #pragma unroll
        for (int s = 0; s < 9; ++s) {
            float a = 0.f;
            for (int ch = 0; ch < 16; ++ch)
                a += part[((size_t)ch * 128 + b * 8 + h) * 81 + t * 9 + s];
            v[s] = a * (SCALE_F / 1024.0f);
        }
        float mx = v[0];
        #pragma unroll
        for (int s = 1; s < 9; ++s) mx = fmaxf(mx, v[s]);
        float den = 0.f;
        #pragma unroll
        for (int s = 0; s < 9; ++s) { v[s] = __expf(v[s] - mx); den += v[s]; }
        float inv = 1.0f / den;
        #pragma unroll
        for (int s = 0; s < 9; ++s) attn_l[h][t][s] = v[s] * inv;
    }
    __syncthreads();
    if (tid < 81) {
        int t = tid / 9, j = tid % 9;
        float o = btmp[j];
        #pragma unroll
        for (int s = 0; s < 9; ++s) {
            float am = 0.f;
            #pragma unroll
            for (int hh = 0; hh < 8; ++hh) am += attn_l[hh][t][s];
            o = fmaf(am * 0.125f, Wtmp[s * 9 + j], o);
        }
        ta[(size_t)b * 81 + t * 9 + j] = o;
    }
}

// ---- K4: in-place temporal mix (layout-agnostic: packing is per-plane permutation)
__global__ __launch_bounds__(256)
void tmix(u16* __restrict__ xb, const float* __restrict__ ta) {
    const int b = blockIdx.y;
    const int tid = threadIdx.x;
    __shared__ float tl[81];
    if (tid < 81) tl[tid] = ta[(size_t)b * 81 + tid];
    __syncthreads();
    size_t off = ((size_t)blockIdx.x * 256 + tid) * 8;
    u16* pb = xb + (size_t)b * 9 * PLANE + off;
    float acc[9][8] = {};
    #pragma unroll
    for (int s = 0; s < 9; ++s) {
        uint4 xv = *(const uint4*)(pb + (size_t)s * PLANE);
        float xf[8]; cvt8(xv, xf);
        #pragma unroll
        for (int t = 0; t < 9; ++t) {
            float w = tl[t * 9 + s];
            #pragma unroll
            for (int e = 0; e < 8; ++e) acc[t][e] = fmaf(w, xf[e], acc[t][e]);
        }
    }
    #pragma unroll
    for (int t = 0; t < 9; ++t)
        *(uint4*)(pb + (size_t)t * PLANE) = pack8(acc[t]);
}

extern "C" void kernel_launch(void* const* d_in, const int* in_sizes, int n_in,
                              void* d_out, int out_size, void* d_ws, size_t ws_size,
                              hipStream_t stream) {
    (void)in_sizes; (void)n_in; (void)out_size; (void)ws_size;
    const float* x    = (const float*)d_in[0];
    const float* Wqkv = (const float*)d_in[1];
    const float* Wtmp = (const float*)d_in[2];
    const float* btmp = (const float*)d_in[3];
    const float* Wout = (const float*)d_in[4];
    const float* bout = (const float*)d_in[5];

    char* ws = (char*)d_ws;
    u16*   xb   = (u16*)ws;                       // 226,492,416 B (frag-packed)
    u16*   BPqk = (u16*)(ws + 226492416ull);      //   2,359,296 B
    u16*   BPo  = (u16*)(ws + 228851712ull);      //   1,179,648 B
    float* part = (float*)(ws + 230031360ull);    //     663,552 B
    float* ta   = (float*)(ws + 230694912ull);    //       5,184 B
    u8*    QK8  = (u8*)d_out;                     // 226,492,416 B fp8 scratch in d_out

    wqk_pack<<<dim3(48, 24), dim3(32, 32), 0, stream>>>(Wqkv, BPqk);
    wvo_gemm<<<dim3(24, 24), dim3(32, 32), 0, stream>>>(Wqkv, Wout, BPo);
    cvt_pack_x<<<dim3(32, 144), 256, 0, stream>>>(x, xb);
    gemm256<0><<<3456, 512, 0, stream>>>(xb, BPqk, (void*)QK8, nullptr, NQK);
    dots_partial<<<dim3(16, 8, 16), 256, 0, stream>>>(QK8, part);
    finalize_ta<<<16, 128, 0, stream>>>(part, Wtmp, btmp, ta);
    tmix<<<dim3(384, 16), 256, 0, stream>>>(xb, ta);
    gemm256<1><<<1728, 512, 0, stream>>>(xb, BPo, d_out, bout, NDIM);
}